// Round 11
// baseline (365.956 us; speedup 1.0000x reference)
//
#include <hip/hip_runtime.h>
#include <hip/hip_bf16.h>
#include <math.h>

typedef unsigned short ushort_t;
typedef __bf16 bf16x8 __attribute__((ext_vector_type(8)));
typedef float f32x4 __attribute__((ext_vector_type(4)));

#define HIDDEN 896
#define NQH 14
#define NKVH 2
#define HD 64
#define SEQ 2048
#define NBATCH 4

__device__ inline ushort_t f2bf(float x) {
  union { float f; unsigned u; } c; c.f = x;
  unsigned r = c.u + 0x7FFFu + ((c.u >> 16) & 1u);
  return (ushort_t)(r >> 16);
}

__device__ inline unsigned pack2bf(float a, float b) {
  union { float f; unsigned u; } ca, cb; ca.f = a; cb.f = b;
  unsigned ua = ca.u + 0x8000u, ub = cb.u + 0x8000u;
  return __builtin_amdgcn_perm(ub, ua, 0x07060302);
}

__device__ inline bf16x8 ldfrag(const ushort_t* p) {
  return *reinterpret_cast<const bf16x8*>(p);
}

__device__ inline void async16(const ushort_t* g, ushort_t* l) {
  __builtin_amdgcn_global_load_lds(
      (const __attribute__((address_space(1))) void*)g,
      (__attribute__((address_space(3))) void*)l, 16, 0, 0);
}

// ---------------- prep ----------------

__device__ inline void transpose_sec(const float* __restrict__ in, ushort_t* __restrict__ out,
                                     int K, int N, int bx, int by) {
  __shared__ float tile[32][33];
  int k0 = by * 32, n0 = bx * 32;
  for (int r = threadIdx.y; r < 32; r += 8) {
    int k = k0 + r, n = n0 + threadIdx.x;
    tile[r][threadIdx.x] = (k < K && n < N) ? in[(size_t)k * N + n] : 0.f;
  }
  __syncthreads();
  for (int r = threadIdx.y; r < 32; r += 8) {
    int n = n0 + r, k = k0 + threadIdx.x;
    if (n < N && k < K) out[(size_t)n * K + k] = f2bf(tile[threadIdx.x][r]);
  }
}

__global__ void k_prep(const float* __restrict__ hidden, ushort_t* __restrict__ hb,
                       const float* __restrict__ Wq, const float* __restrict__ Wk,
                       const float* __restrict__ Wv, const float* __restrict__ Wo,
                       ushort_t* __restrict__ wT, ushort_t* __restrict__ woT,
                       float2* __restrict__ ctab) {
  const int blk = blockIdx.x;
  const int tid = threadIdx.y * 32 + threadIdx.x;
  if (blk < 7168) {
    int i = blk * 256 + tid;
    float4 v = reinterpret_cast<const float4*>(hidden)[i];
    ushort4 o;
    o.x = f2bf(v.x); o.y = f2bf(v.y); o.z = f2bf(v.z); o.w = f2bf(v.w);
    reinterpret_cast<ushort4*>(hb)[i] = o;
  } else if (blk < 7424) {
    int idx = (blk - 7168) * 256 + tid;
    int s = idx >> 5, dp = idx & 31;
    float inv = exp2f(-(float)dp * 0.41524101186092596f);
    float ang = (float)s * inv;
    float sn, cn;
    sincosf(ang, &sn, &cn);
    ctab[idx] = make_float2(cn, sn);
  } else if (blk < 8208) {
    int t = blk - 7424;
    transpose_sec(Wq, wT, 896, 896, t % 28, t / 28);
  } else if (blk < 8320) {
    int t = blk - 8208;
    transpose_sec(Wk, wT + (size_t)896 * 896, 896, 128, t % 4, t / 4);
  } else if (blk < 8432) {
    int t = blk - 8320;
    transpose_sec(Wv, wT + (size_t)1024 * 896, 896, 128, t % 4, t / 4);
  } else {
    int t = blk - 8432;
    transpose_sec(Wo, woT, 896, 896, t % 28, t / 28);
  }
}

// ---------------- QKV projection + RoPE (64x128 tiles, BK=64, swizzled LDS) ----------
// grid: 1152 blocks 1D (128 m-tiles x 9 n-sections), XCD-swizzled. [R9 proven config]
__global__ __launch_bounds__(256) void k_qkv(
    const ushort_t* __restrict__ hb,
    const ushort_t* __restrict__ wT,
    const int* __restrict__ pos_ids,
    const float2* __restrict__ ctab,
    ushort_t* __restrict__ Qg,
    ushort_t* __restrict__ Kg,
    ushort_t* __restrict__ Vtg) {
  __shared__ ushort_t smem[12288];  // sa [0,4096) 64x64, sbb [4096,12288) 128x64
  ushort_t* sa = smem;
  ushort_t* sbb = smem + 4096;

  const int f = blockIdx.x;
  const int x = f & 7, s8 = f >> 3;       // s8: 0..143
  const int sect = s8 % 9;
  const int mt = (s8 / 9) * 8 + x;        // 0..127
  const int nt0 = sect * 128;
  const int m0 = mt * 64;
  const int tid = threadIdx.x;
  const int wave = tid >> 6, lane = tid & 63;
  const int l15 = lane & 15, quad = lane >> 4;
  const int wm = wave >> 1, wn = wave & 1;
  const int sw = l15 & 7;

  f32x4 acc[2][4];
  const f32x4 z4 = {0.f, 0.f, 0.f, 0.f};
#pragma unroll
  for (int a = 0; a < 2; ++a)
#pragma unroll
    for (int b = 0; b < 4; ++b) acc[a][b] = z4;

  for (int kt = 0; kt < 14; ++kt) {
    const int k0 = kt * 64;
    __syncthreads();
#pragma unroll
    for (int i = 0; i < 2; ++i) {
      int id = i * 256 + tid;
      int row = id >> 3;
      int cs = (id & 7) ^ (row & 7);
      async16(hb + (size_t)(m0 + row) * HIDDEN + k0 + cs * 8, sa + (i * 256 + wave * 64) * 8);
    }
#pragma unroll
    for (int i = 0; i < 4; ++i) {
      int id = i * 256 + tid;
      int row = id >> 3;
      int cs = (id & 7) ^ (row & 7);
      async16(wT + (size_t)(nt0 + row) * HIDDEN + k0 + cs * 8, sbb + (i * 256 + wave * 64) * 8);
    }
    __syncthreads();
    bf16x8 af[2][2], bf[4][2];
#pragma unroll
    for (int kc = 0; kc < 2; ++kc) {
      int c = kc * 4 + quad;
#pragma unroll
      for (int mb = 0; mb < 2; ++mb)
        af[mb][kc] = ldfrag(sa + ((wm * 32 + mb * 16 + l15) * 8 + (c ^ sw)) * 8);
#pragma unroll
      for (int nb = 0; nb < 4; ++nb)
        bf[nb][kc] = ldfrag(sbb + ((wn * 64 + nb * 16 + l15) * 8 + (c ^ sw)) * 8);
    }
#pragma unroll
    for (int mb = 0; mb < 2; ++mb)
#pragma unroll
      for (int nb = 0; nb < 4; ++nb) {
        acc[mb][nb] = __builtin_amdgcn_mfma_f32_16x16x32_bf16(af[mb][0], bf[nb][0], acc[mb][nb], 0, 0, 0);
        acc[mb][nb] = __builtin_amdgcn_mfma_f32_16x16x32_bf16(af[mb][1], bf[nb][1], acc[mb][nb], 0, 0, 0);
      }
  }

  if (sect < 8) {
    const bool isQ = sect < 7;
    const float csc = isQ ? 0.125f * 1.4426950408889634f : 1.0f;
    ushort_t* dst = isQ ? Qg : Kg;
    const int nheads = isQ ? NQH : NKVH;
    const int hh = isQ ? sect * 2 + wn : wn;
#pragma unroll
    for (int mb = 0; mb < 2; ++mb)
#pragma unroll
      for (int r = 0; r < 4; ++r) {
        int token = m0 + wm * 32 + mb * 16 + quad * 4 + r;
        int b = token >> 11, s = token & 2047;
        int pos = pos_ids[token];
        size_t base = ((size_t)(b * nheads + hh) * SEQ + s) * HD;
#pragma unroll
        for (int nb = 0; nb < 2; ++nb) {
          float2 cs = ctab[pos * 32 + nb * 16 + l15];
          float x0 = acc[mb][nb][r];
          float x1 = acc[mb][nb + 2][r];
          float y0 = (x0 * cs.x - x1 * cs.y) * csc;
          float y1 = (x1 * cs.x + x0 * cs.y) * csc;
          dst[base + nb * 16 + l15]      = f2bf(y0);
          dst[base + nb * 16 + l15 + 32] = f2bf(y1);
        }
      }
  } else {
    __syncthreads();
    ushort_t* vt = smem;  // 128 rows x 64 tokens = 16384B
#pragma unroll
    for (int mb = 0; mb < 2; ++mb) {
      int tl = wm * 32 + mb * 16 + quad * 4;
      int chunk = tl >> 3, ofs = tl & 7;
#pragma unroll
      for (int nb = 0; nb < 4; ++nb) {
        int row = wn * 64 + nb * 16 + l15;
        int slot = chunk ^ (row & 7);
        ushort_t* p = vt + row * 64 + slot * 8 + ofs;
        *reinterpret_cast<unsigned*>(p)     = pack2bf(acc[mb][nb][0], acc[mb][nb][1]);
        *reinterpret_cast<unsigned*>(p + 2) = pack2bf(acc[mb][nb][2], acc[mb][nb][3]);
      }
    }
    __syncthreads();
    const int bb = m0 >> 11, s0 = m0 & 2047;
#pragma unroll
    for (int i = 0; i < 4; ++i) {
      int id = i * 256 + tid;
      int row = id >> 3, ch = id & 7;
      int kvh = row >> 6, d = row & 63;
      int slot = ch ^ (row & 7);
      uint4 v = *reinterpret_cast<const uint4*>(vt + row * 64 + slot * 8);
      *reinterpret_cast<uint4*>(Vtg + ((size_t)(bb * NKVH + kvh) * HD + d) * SEQ + s0 + ch * 8) = v;
    }
  }
}

// ---------------- flash attention (direct-global K/V, pbuf-only LDS, no barriers) ----
// LDS-pipe analysis (R10): staged kbuf/vbuf gave ~134% per-CU LDS demand (4 waves
// re-read identical K/V rows). K[s][d] and Vt[d][s] are 16B/lane contiguous in
// global -> read fragments straight from L2; LDS keeps only per-wave pbuf.
// grid: 896 blocks x 256 threads. XCD x owns (b,kvh): b=x>>1, kvh=x&1. 4 waves x 32q.
__global__ __launch_bounds__(256) void k_attn(
    const ushort_t* __restrict__ Qg,
    const ushort_t* __restrict__ Kg,
    const ushort_t* __restrict__ Vtg,
    ushort_t* __restrict__ attn) {
  __shared__ ushort_t pbuf[4][32 * 72];

  const int f = blockIdx.x;
  const int x = f & 7, s8 = f >> 3;     // s8: 0..111
  const int lh = s8 % 7;
  const int qt = s8 / 7;                // 0..15
  const int b = x >> 1, kvh = x & 1;
  const int h = kvh * 7 + lh;
  const int bh = b * NQH + h;
  const int tid = threadIdx.x;
  const int wave = tid >> 6, lane = tid & 63;
  const int l15 = lane & 15, quad = lane >> 4;
  const int q0 = qt * 128;

  bf16x8 qf[2][2];
#pragma unroll
  for (int qs = 0; qs < 2; ++qs) {
    const size_t qb = ((size_t)bh * SEQ + q0 + wave * 32 + qs * 16 + l15) * HD + quad * 8;
    qf[qs][0] = ldfrag(Qg + qb);
    qf[qs][1] = ldfrag(Qg + qb + 32);
  }

  const ushort_t* Kb = Kg + (size_t)(b * NKVH + kvh) * SEQ * HD;   // [2048][64]
  const ushort_t* Vb = Vtg + (size_t)(b * NKVH + kvh) * HD * SEQ;  // [64][2048]

  float l_part[2] = {0.f, 0.f};
  f32x4 o[2][4];
  const f32x4 z4 = {0.f, 0.f, 0.f, 0.f};
#pragma unroll
  for (int qs = 0; qs < 2; ++qs)
#pragma unroll
    for (int nb = 0; nb < 4; ++nb) o[qs][nb] = z4;

  ushort_t* pw = pbuf[wave];

  for (int jt = 0; jt < 32; ++jt) {
    const int s0 = jt * 64;

    // S^T = K x Q^T ; kf direct from global (16B/lane contiguous; L2-resident)
#pragma unroll
    for (int nb = 0; nb < 4; ++nb) {
      const ushort_t* kr = Kb + (size_t)(s0 + nb * 16 + l15) * HD + quad * 8;
      bf16x8 kf0 = ldfrag(kr);
      bf16x8 kf1 = ldfrag(kr + 32);
#pragma unroll
      for (int qs = 0; qs < 2; ++qs) {
        f32x4 t = z4;
        t = __builtin_amdgcn_mfma_f32_16x16x32_bf16(kf0, qf[qs][0], t, 0, 0, 0);
        t = __builtin_amdgcn_mfma_f32_16x16x32_bf16(kf1, qf[qs][1], t, 0, 0, 0);
        float p0 = __builtin_amdgcn_exp2f(t[0]);
        float p1 = __builtin_amdgcn_exp2f(t[1]);
        float p2 = __builtin_amdgcn_exp2f(t[2]);
        float p3 = __builtin_amdgcn_exp2f(t[3]);
        l_part[qs] += (p0 + p1) + (p2 + p3);
        uint2 d;
        d.x = pack2bf(p0, p1);
        d.y = pack2bf(p2, p3);
        *reinterpret_cast<uint2*>(pw + (qs * 16 + l15) * 72 + nb * 16 + quad * 4) = d;
      }
    }

    // P fragments (per-wave pbuf; wave-internal dependency only — no barrier)
    bf16x8 pf[2][2];
#pragma unroll
    for (int qs = 0; qs < 2; ++qs) {
      pf[qs][0] = ldfrag(pw + (qs * 16 + l15) * 72 + quad * 8);
      pf[qs][1] = ldfrag(pw + (qs * 16 + l15) * 72 + 32 + quad * 8);
    }

    // PV: vf direct from global (Vt rows along s -> 16B/lane contiguous)
#pragma unroll
    for (int nb = 0; nb < 4; ++nb) {
      const ushort_t* vr = Vb + (size_t)(nb * 16 + l15) * SEQ + s0 + quad * 8;
      bf16x8 vf0 = ldfrag(vr);
      bf16x8 vf1 = ldfrag(vr + 32);
#pragma unroll
      for (int qs = 0; qs < 2; ++qs) {
        o[qs][nb] = __builtin_amdgcn_mfma_f32_16x16x32_bf16(pf[qs][0], vf0, o[qs][nb], 0, 0, 0);
        o[qs][nb] = __builtin_amdgcn_mfma_f32_16x16x32_bf16(pf[qs][1], vf1, o[qs][nb], 0, 0, 0);
      }
    }
  }

#pragma unroll
  for (int qs = 0; qs < 2; ++qs) {
    float s = l_part[qs];
    s += __shfl_xor(s, 16);
    s += __shfl_xor(s, 32);
    l_part[qs] = s;
  }

#pragma unroll
  for (int qs = 0; qs < 2; ++qs) {
    float il = 1.0f / l_part[qs];
#pragma unroll
    for (int r = 0; r < 4; ++r) {
      float inv = __shfl(il, quad * 4 + r);
      int qg = q0 + wave * 32 + qs * 16 + quad * 4 + r;
#pragma unroll
      for (int nb = 0; nb < 4; ++nb) {
        float val = o[qs][nb][r] * inv;
        attn[(size_t)(b * SEQ + qg) * (NQH * HD) + h * HD + nb * 16 + l15] = f2bf(val);
      }
    }
  }
}

// ---------------- output projection (64x128 tiles, BK=64, swizzled) ----------------
// grid: 896 blocks 1D (128 m-tiles x 7 n-sections). [R9 proven config]
__global__ __launch_bounds__(256) void k_oproj(
    const ushort_t* __restrict__ attn,
    const ushort_t* __restrict__ woT,
    float* __restrict__ out) {
  __shared__ ushort_t smem[12288];
  ushort_t* sa = smem;
  ushort_t* sbb = smem + 4096;

  const int f = blockIdx.x;
  const int x = f & 7, s8 = f >> 3;   // s8: 0..111
  const int n_sect = s8 % 7;
  const int mt = (s8 / 7) * 8 + x;    // 0..127
  const int n0 = n_sect * 128;
  const int m0 = mt * 64;
  const int tid = threadIdx.x;
  const int wave = tid >> 6, lane = tid & 63;
  const int l15 = lane & 15, quad = lane >> 4;
  const int wm = wave >> 1, wn = wave & 1;
  const int sw = l15 & 7;

  f32x4 acc[2][4];
  const f32x4 z4 = {0.f, 0.f, 0.f, 0.f};
#pragma unroll
  for (int a = 0; a < 2; ++a)
#pragma unroll
    for (int b = 0; b < 4; ++b) acc[a][b] = z4;

  for (int kt = 0; kt < 14; ++kt) {
    const int k0 = kt * 64;
    __syncthreads();
#pragma unroll
    for (int i = 0; i < 2; ++i) {
      int id = i * 256 + tid;
      int row = id >> 3;
      int cs = (id & 7) ^ (row & 7);
      async16(attn + (size_t)(m0 + row) * HIDDEN + k0 + cs * 8, sa + (i * 256 + wave * 64) * 8);
    }
#pragma unroll
    for (int i = 0; i < 4; ++i) {
      int id = i * 256 + tid;
      int row = id >> 3;
      int cs = (id & 7) ^ (row & 7);
      async16(woT + (size_t)(n0 + row) * HIDDEN + k0 + cs * 8, sbb + (i * 256 + wave * 64) * 8);
    }
    __syncthreads();
    bf16x8 af[2][2], bf[4][2];
#pragma unroll
    for (int kc = 0; kc < 2; ++kc) {
      int c = kc * 4 + quad;
#pragma unroll
      for (int mb = 0; mb < 2; ++mb)
        af[mb][kc] = ldfrag(sa + ((wm * 32 + mb * 16 + l15) * 8 + (c ^ sw)) * 8);
#pragma unroll
      for (int nb = 0; nb < 4; ++nb)
        bf[nb][kc] = ldfrag(sbb + ((wn * 64 + nb * 16 + l15) * 8 + (c ^ sw)) * 8);
    }
#pragma unroll
    for (int mb = 0; mb < 2; ++mb)
#pragma unroll
      for (int nb = 0; nb < 4; ++nb) {
        acc[mb][nb] = __builtin_amdgcn_mfma_f32_16x16x32_bf16(af[mb][0], bf[nb][0], acc[mb][nb], 0, 0, 0);
        acc[mb][nb] = __builtin_amdgcn_mfma_f32_16x16x32_bf16(af[mb][1], bf[nb][1], acc[mb][nb], 0, 0, 0);
      }
  }

#pragma unroll
  for (int mb = 0; mb < 2; ++mb)
#pragma unroll
    for (int nb = 0; nb < 4; ++nb)
#pragma unroll
      for (int r = 0; r < 4; ++r)
        out[(size_t)(m0 + wm * 32 + mb * 16 + quad * 4 + r) * HIDDEN +
            n0 + wn * 64 + nb * 16 + l15] = acc[mb][nb][r];
}

// ---------------- launch ----------------

extern "C" void kernel_launch(void* const* d_in, const int* in_sizes, int n_in,
                              void* d_out, int out_size, void* d_ws, size_t ws_size,
                              hipStream_t stream) {
  (void)in_sizes; (void)n_in; (void)out_size; (void)ws_size;
  const float* hidden = (const float*)d_in[0];
  const int* pos      = (const int*)d_in[1];
  const float* Wq     = (const float*)d_in[2];
  const float* Wk     = (const float*)d_in[3];
  const float* Wv     = (const float*)d_in[4];
  const float* Wo     = (const float*)d_in[5];
  float* out = (float*)d_out;

  char* ws = (char*)d_ws;
  ushort_t* hb   = (ushort_t*)(ws);               // [8192][896] bf16   14,680,064
  ushort_t* wT   = (ushort_t*)(ws + 14680064);    // [1152][896] bf16    2,064,384
  float2*   ctab = (float2*)  (ws + 16744448);    // [2048][32]            524,288
  ushort_t* Qg   = (ushort_t*)(ws + 17268736);    // [4][14][2048][64]  14,680,064
  ushort_t* Kg   = (ushort_t*)(ws + 31948800);    // [4][2][2048][64]    2,097,152
  ushort_t* Vtg  = (ushort_t*)(ws + 34045952);    // [4][2][64][2048]    2,097,152
  ushort_t* attn = (ushort_t*)(ws + 36143104);    // [8192][896] bf16   14,680,064
  ushort_t* woT  = (ushort_t*)(ws + 50823168);    // [896][896] bf16     1,605,632

  k_prep<<<9216, dim3(32, 8), 0, stream>>>(hidden, hb, Wq, Wk, Wv, Wo, wT, woT, ctab);
  k_qkv<<<1152, 256, 0, stream>>>(hb, wT, pos, ctab, Qg, Kg, Vtg);
  k_attn<<<896, 256, 0, stream>>>(Qg, Kg, Vtg, attn);
  k_oproj<<<896, 256, 0, stream>>>(attn, woT, out);
}

// Round 12
// 364.171 us; speedup vs baseline: 1.0049x; 1.0049x over previous
//
#include <hip/hip_runtime.h>
#include <hip/hip_bf16.h>
#include <math.h>

typedef unsigned short ushort_t;
typedef __bf16 bf16x8 __attribute__((ext_vector_type(8)));
typedef float f32x4 __attribute__((ext_vector_type(4)));

#define HIDDEN 896
#define NQH 14
#define NKVH 2
#define HD 64
#define SEQ 2048
#define NBATCH 4

__device__ inline ushort_t f2bf(float x) {
  union { float f; unsigned u; } c; c.f = x;
  unsigned r = c.u + 0x7FFFu + ((c.u >> 16) & 1u);
  return (ushort_t)(r >> 16);
}

__device__ inline unsigned pack2bf(float a, float b) {
  union { float f; unsigned u; } ca, cb; ca.f = a; cb.f = b;
  unsigned ua = ca.u + 0x8000u, ub = cb.u + 0x8000u;
  return __builtin_amdgcn_perm(ub, ua, 0x07060302);
}

__device__ inline bf16x8 ldfrag(const ushort_t* p) {
  return *reinterpret_cast<const bf16x8*>(p);
}

__device__ inline void async16(const ushort_t* g, ushort_t* l) {
  __builtin_amdgcn_global_load_lds(
      (const __attribute__((address_space(1))) void*)g,
      (__attribute__((address_space(3))) void*)l, 16, 0, 0);
}

// ---------------- prep ----------------

__device__ inline void transpose_sec(const float* __restrict__ in, ushort_t* __restrict__ out,
                                     int K, int N, int bx, int by) {
  __shared__ float tile[32][33];
  int k0 = by * 32, n0 = bx * 32;
  for (int r = threadIdx.y; r < 32; r += 8) {
    int k = k0 + r, n = n0 + threadIdx.x;
    tile[r][threadIdx.x] = (k < K && n < N) ? in[(size_t)k * N + n] : 0.f;
  }
  __syncthreads();
  for (int r = threadIdx.y; r < 32; r += 8) {
    int n = n0 + r, k = k0 + threadIdx.x;
    if (n < N && k < K) out[(size_t)n * K + k] = f2bf(tile[threadIdx.x][r]);
  }
}

__global__ void k_prep(const float* __restrict__ hidden, ushort_t* __restrict__ hb,
                       const float* __restrict__ Wq, const float* __restrict__ Wk,
                       const float* __restrict__ Wv, const float* __restrict__ Wo,
                       ushort_t* __restrict__ wT, ushort_t* __restrict__ woT,
                       float2* __restrict__ ctab) {
  const int blk = blockIdx.x;
  const int tid = threadIdx.y * 32 + threadIdx.x;
  if (blk < 7168) {
    int i = blk * 256 + tid;
    float4 v = reinterpret_cast<const float4*>(hidden)[i];
    ushort4 o;
    o.x = f2bf(v.x); o.y = f2bf(v.y); o.z = f2bf(v.z); o.w = f2bf(v.w);
    reinterpret_cast<ushort4*>(hb)[i] = o;
  } else if (blk < 7424) {
    int idx = (blk - 7168) * 256 + tid;
    int s = idx >> 5, dp = idx & 31;
    float inv = exp2f(-(float)dp * 0.41524101186092596f);
    float ang = (float)s * inv;
    float sn, cn;
    sincosf(ang, &sn, &cn);
    ctab[idx] = make_float2(cn, sn);
  } else if (blk < 8208) {
    int t = blk - 7424;
    transpose_sec(Wq, wT, 896, 896, t % 28, t / 28);
  } else if (blk < 8320) {
    int t = blk - 8208;
    transpose_sec(Wk, wT + (size_t)896 * 896, 896, 128, t % 4, t / 4);
  } else if (blk < 8432) {
    int t = blk - 8320;
    transpose_sec(Wv, wT + (size_t)1024 * 896, 896, 128, t % 4, t / 4);
  } else {
    int t = blk - 8432;
    transpose_sec(Wo, woT, 896, 896, t % 28, t / 28);
  }
}

// ---------------- QKV projection + RoPE (64x128 tiles, BK=64, swizzled LDS) ----------
// grid: 1152 blocks 1D (128 m-tiles x 9 n-sections), XCD-swizzled. [R9 proven config]
__global__ __launch_bounds__(256) void k_qkv(
    const ushort_t* __restrict__ hb,
    const ushort_t* __restrict__ wT,
    const int* __restrict__ pos_ids,
    const float2* __restrict__ ctab,
    ushort_t* __restrict__ Qg,
    ushort_t* __restrict__ Kg,
    ushort_t* __restrict__ Vtg) {
  __shared__ ushort_t smem[12288];  // sa [0,4096) 64x64, sbb [4096,12288) 128x64
  ushort_t* sa = smem;
  ushort_t* sbb = smem + 4096;

  const int f = blockIdx.x;
  const int x = f & 7, s8 = f >> 3;       // s8: 0..143
  const int sect = s8 % 9;
  const int mt = (s8 / 9) * 8 + x;        // 0..127
  const int nt0 = sect * 128;
  const int m0 = mt * 64;
  const int tid = threadIdx.x;
  const int wave = tid >> 6, lane = tid & 63;
  const int l15 = lane & 15, quad = lane >> 4;
  const int wm = wave >> 1, wn = wave & 1;
  const int sw = l15 & 7;

  f32x4 acc[2][4];
  const f32x4 z4 = {0.f, 0.f, 0.f, 0.f};
#pragma unroll
  for (int a = 0; a < 2; ++a)
#pragma unroll
    for (int b = 0; b < 4; ++b) acc[a][b] = z4;

  for (int kt = 0; kt < 14; ++kt) {
    const int k0 = kt * 64;
    __syncthreads();
#pragma unroll
    for (int i = 0; i < 2; ++i) {
      int id = i * 256 + tid;
      int row = id >> 3;
      int cs = (id & 7) ^ (row & 7);
      async16(hb + (size_t)(m0 + row) * HIDDEN + k0 + cs * 8, sa + (i * 256 + wave * 64) * 8);
    }
#pragma unroll
    for (int i = 0; i < 4; ++i) {
      int id = i * 256 + tid;
      int row = id >> 3;
      int cs = (id & 7) ^ (row & 7);
      async16(wT + (size_t)(nt0 + row) * HIDDEN + k0 + cs * 8, sbb + (i * 256 + wave * 64) * 8);
    }
    __syncthreads();
    bf16x8 af[2][2], bf[4][2];
#pragma unroll
    for (int kc = 0; kc < 2; ++kc) {
      int c = kc * 4 + quad;
#pragma unroll
      for (int mb = 0; mb < 2; ++mb)
        af[mb][kc] = ldfrag(sa + ((wm * 32 + mb * 16 + l15) * 8 + (c ^ sw)) * 8);
#pragma unroll
      for (int nb = 0; nb < 4; ++nb)
        bf[nb][kc] = ldfrag(sbb + ((wn * 64 + nb * 16 + l15) * 8 + (c ^ sw)) * 8);
    }
#pragma unroll
    for (int mb = 0; mb < 2; ++mb)
#pragma unroll
      for (int nb = 0; nb < 4; ++nb) {
        acc[mb][nb] = __builtin_amdgcn_mfma_f32_16x16x32_bf16(af[mb][0], bf[nb][0], acc[mb][nb], 0, 0, 0);
        acc[mb][nb] = __builtin_amdgcn_mfma_f32_16x16x32_bf16(af[mb][1], bf[nb][1], acc[mb][nb], 0, 0, 0);
      }
  }

  if (sect < 8) {
    const bool isQ = sect < 7;
    const float csc = isQ ? 0.125f * 1.4426950408889634f : 1.0f;
    ushort_t* dst = isQ ? Qg : Kg;
    const int nheads = isQ ? NQH : NKVH;
    const int hh = isQ ? sect * 2 + wn : wn;
#pragma unroll
    for (int mb = 0; mb < 2; ++mb)
#pragma unroll
      for (int r = 0; r < 4; ++r) {
        int token = m0 + wm * 32 + mb * 16 + quad * 4 + r;
        int b = token >> 11, s = token & 2047;
        int pos = pos_ids[token];
        size_t base = ((size_t)(b * nheads + hh) * SEQ + s) * HD;
#pragma unroll
        for (int nb = 0; nb < 2; ++nb) {
          float2 cs = ctab[pos * 32 + nb * 16 + l15];
          float x0 = acc[mb][nb][r];
          float x1 = acc[mb][nb + 2][r];
          float y0 = (x0 * cs.x - x1 * cs.y) * csc;
          float y1 = (x1 * cs.x + x0 * cs.y) * csc;
          dst[base + nb * 16 + l15]      = f2bf(y0);
          dst[base + nb * 16 + l15 + 32] = f2bf(y1);
        }
      }
  } else {
    __syncthreads();
    ushort_t* vt = smem;  // 128 rows x 64 tokens = 16384B
#pragma unroll
    for (int mb = 0; mb < 2; ++mb) {
      int tl = wm * 32 + mb * 16 + quad * 4;
      int chunk = tl >> 3, ofs = tl & 7;
#pragma unroll
      for (int nb = 0; nb < 4; ++nb) {
        int row = wn * 64 + nb * 16 + l15;
        int slot = chunk ^ (row & 7);
        ushort_t* p = vt + row * 64 + slot * 8 + ofs;
        *reinterpret_cast<unsigned*>(p)     = pack2bf(acc[mb][nb][0], acc[mb][nb][1]);
        *reinterpret_cast<unsigned*>(p + 2) = pack2bf(acc[mb][nb][2], acc[mb][nb][3]);
      }
    }
    __syncthreads();
    const int bb = m0 >> 11, s0 = m0 & 2047;
#pragma unroll
    for (int i = 0; i < 4; ++i) {
      int id = i * 256 + tid;
      int row = id >> 3, ch = id & 7;
      int kvh = row >> 6, d = row & 63;
      int slot = ch ^ (row & 7);
      uint4 v = *reinterpret_cast<const uint4*>(vt + row * 64 + slot * 8);
      *reinterpret_cast<uint4*>(Vtg + ((size_t)(bb * NKVH + kvh) * HD + d) * SEQ + s0 + ch * 8) = v;
    }
  }
}

// ---------------- flash attention (direct-global K/V + REGISTER PIPELINING) ----------
// R11 diagnosis: just-in-time global fragment loads serialize (~300cyc x 16/jt =
// 5270 cyc/jt measured). Fix: K frags double-buffered in registers with 1-iteration
// prefetch distance; V frags issued at iteration top, consumed after softmax
// (~300cyc natural hiding). No barriers in jt loop; LDS = per-wave pbuf only.
// grid: 896 blocks x 256 threads. XCD x owns (b,kvh). 4 waves x 32q.
__global__ __launch_bounds__(256) void k_attn(
    const ushort_t* __restrict__ Qg,
    const ushort_t* __restrict__ Kg,
    const ushort_t* __restrict__ Vtg,
    ushort_t* __restrict__ attn) {
  __shared__ ushort_t pbuf[4][32 * 72];

  const int f = blockIdx.x;
  const int x = f & 7, s8 = f >> 3;     // s8: 0..111
  const int lh = s8 % 7;
  const int qt = s8 / 7;                // 0..15
  const int b = x >> 1, kvh = x & 1;
  const int h = kvh * 7 + lh;
  const int bh = b * NQH + h;
  const int tid = threadIdx.x;
  const int wave = tid >> 6, lane = tid & 63;
  const int l15 = lane & 15, quad = lane >> 4;
  const int q0 = qt * 128;

  bf16x8 qf[2][2];
#pragma unroll
  for (int qs = 0; qs < 2; ++qs) {
    const size_t qb = ((size_t)bh * SEQ + q0 + wave * 32 + qs * 16 + l15) * HD + quad * 8;
    qf[qs][0] = ldfrag(Qg + qb);
    qf[qs][1] = ldfrag(Qg + qb + 32);
  }

  const ushort_t* Kb = Kg + (size_t)(b * NKVH + kvh) * SEQ * HD;   // [2048][64]
  const ushort_t* Vb = Vtg + (size_t)(b * NKVH + kvh) * HD * SEQ;  // [64][2048]

  float l_part[2] = {0.f, 0.f};
  f32x4 o[2][4];
  const f32x4 z4 = {0.f, 0.f, 0.f, 0.f};
#pragma unroll
  for (int qs = 0; qs < 2; ++qs)
#pragma unroll
    for (int nb = 0; nb < 4; ++nb) o[qs][nb] = z4;

  ushort_t* pw = pbuf[wave];

  // K-fragment register double-buffer: preload jt=0
  bf16x8 kreg[2][4][2];
#pragma unroll
  for (int nb = 0; nb < 4; ++nb) {
    const ushort_t* kr = Kb + (size_t)(nb * 16 + l15) * HD + quad * 8;
    kreg[0][nb][0] = ldfrag(kr);
    kreg[0][nb][1] = ldfrag(kr + 32);
  }

#pragma unroll 2
  for (int jt = 0; jt < 32; ++jt) {
    const int cur = jt & 1, nxt = cur ^ 1;
    const int s0 = jt * 64;

    // prefetch next jt's K fragments (consumed one full iteration later)
    if (jt + 1 < 32) {
      const int s1 = s0 + 64;
#pragma unroll
      for (int nb = 0; nb < 4; ++nb) {
        const ushort_t* kr = Kb + (size_t)(s1 + nb * 16 + l15) * HD + quad * 8;
        kreg[nxt][nb][0] = ldfrag(kr);
        kreg[nxt][nb][1] = ldfrag(kr + 32);
      }
    }

    // V fragments for CURRENT jt: issued now, consumed after QK+softmax (~300cyc)
    bf16x8 vf[4][2];
#pragma unroll
    for (int nb = 0; nb < 4; ++nb) {
      const ushort_t* vr = Vb + (size_t)(nb * 16 + l15) * SEQ + s0 + quad * 8;
      vf[nb][0] = ldfrag(vr);
      vf[nb][1] = ldfrag(vr + 32);
    }

    // S^T = K x Q^T with prefetched K fragments
#pragma unroll
    for (int nb = 0; nb < 4; ++nb) {
#pragma unroll
      for (int qs = 0; qs < 2; ++qs) {
        f32x4 t = z4;
        t = __builtin_amdgcn_mfma_f32_16x16x32_bf16(kreg[cur][nb][0], qf[qs][0], t, 0, 0, 0);
        t = __builtin_amdgcn_mfma_f32_16x16x32_bf16(kreg[cur][nb][1], qf[qs][1], t, 0, 0, 0);
        float p0 = __builtin_amdgcn_exp2f(t[0]);
        float p1 = __builtin_amdgcn_exp2f(t[1]);
        float p2 = __builtin_amdgcn_exp2f(t[2]);
        float p3 = __builtin_amdgcn_exp2f(t[3]);
        l_part[qs] += (p0 + p1) + (p2 + p3);
        uint2 d;
        d.x = pack2bf(p0, p1);
        d.y = pack2bf(p2, p3);
        *reinterpret_cast<uint2*>(pw + (qs * 16 + l15) * 72 + nb * 16 + quad * 4) = d;
      }
    }

    // P fragments (per-wave pbuf; wave-internal lgkmcnt only)
    bf16x8 pf[2][2];
#pragma unroll
    for (int qs = 0; qs < 2; ++qs) {
      pf[qs][0] = ldfrag(pw + (qs * 16 + l15) * 72 + quad * 8);
      pf[qs][1] = ldfrag(pw + (qs * 16 + l15) * 72 + 32 + quad * 8);
    }

    // PV with register V fragments
#pragma unroll
    for (int nb = 0; nb < 4; ++nb) {
#pragma unroll
      for (int qs = 0; qs < 2; ++qs) {
        o[qs][nb] = __builtin_amdgcn_mfma_f32_16x16x32_bf16(pf[qs][0], vf[nb][0], o[qs][nb], 0, 0, 0);
        o[qs][nb] = __builtin_amdgcn_mfma_f32_16x16x32_bf16(pf[qs][1], vf[nb][1], o[qs][nb], 0, 0, 0);
      }
    }
  }

#pragma unroll
  for (int qs = 0; qs < 2; ++qs) {
    float s = l_part[qs];
    s += __shfl_xor(s, 16);
    s += __shfl_xor(s, 32);
    l_part[qs] = s;
  }

#pragma unroll
  for (int qs = 0; qs < 2; ++qs) {
    float il = 1.0f / l_part[qs];
#pragma unroll
    for (int r = 0; r < 4; ++r) {
      float inv = __shfl(il, quad * 4 + r);
      int qg = q0 + wave * 32 + qs * 16 + quad * 4 + r;
#pragma unroll
      for (int nb = 0; nb < 4; ++nb) {
        float val = o[qs][nb][r] * inv;
        attn[(size_t)(b * SEQ + qg) * (NQH * HD) + h * HD + nb * 16 + l15] = f2bf(val);
      }
    }
  }
}

// ---------------- output projection (64x128 tiles, BK=64, swizzled) ----------------
// grid: 896 blocks 1D (128 m-tiles x 7 n-sections). [R9 proven config]
__global__ __launch_bounds__(256) void k_oproj(
    const ushort_t* __restrict__ attn,
    const ushort_t* __restrict__ woT,
    float* __restrict__ out) {
  __shared__ ushort_t smem[12288];
  ushort_t* sa = smem;
  ushort_t* sbb = smem + 4096;

  const int f = blockIdx.x;
  const int x = f & 7, s8 = f >> 3;   // s8: 0..111
  const int n_sect = s8 % 7;
  const int mt = (s8 / 7) * 8 + x;    // 0..127
  const int n0 = n_sect * 128;
  const int m0 = mt * 64;
  const int tid = threadIdx.x;
  const int wave = tid >> 6, lane = tid & 63;
  const int l15 = lane & 15, quad = lane >> 4;
  const int wm = wave >> 1, wn = wave & 1;
  const int sw = l15 & 7;

  f32x4 acc[2][4];
  const f32x4 z4 = {0.f, 0.f, 0.f, 0.f};
#pragma unroll
  for (int a = 0; a < 2; ++a)
#pragma unroll
    for (int b = 0; b < 4; ++b) acc[a][b] = z4;

  for (int kt = 0; kt < 14; ++kt) {
    const int k0 = kt * 64;
    __syncthreads();
#pragma unroll
    for (int i = 0; i < 2; ++i) {
      int id = i * 256 + tid;
      int row = id >> 3;
      int cs = (id & 7) ^ (row & 7);
      async16(attn + (size_t)(m0 + row) * HIDDEN + k0 + cs * 8, sa + (i * 256 + wave * 64) * 8);
    }
#pragma unroll
    for (int i = 0; i < 4; ++i) {
      int id = i * 256 + tid;
      int row = id >> 3;
      int cs = (id & 7) ^ (row & 7);
      async16(woT + (size_t)(n0 + row) * HIDDEN + k0 + cs * 8, sbb + (i * 256 + wave * 64) * 8);
    }
    __syncthreads();
    bf16x8 af[2][2], bf[4][2];
#pragma unroll
    for (int kc = 0; kc < 2; ++kc) {
      int c = kc * 4 + quad;
#pragma unroll
      for (int mb = 0; mb < 2; ++mb)
        af[mb][kc] = ldfrag(sa + ((wm * 32 + mb * 16 + l15) * 8 + (c ^ sw)) * 8);
#pragma unroll
      for (int nb = 0; nb < 4; ++nb)
        bf[nb][kc] = ldfrag(sbb + ((wn * 64 + nb * 16 + l15) * 8 + (c ^ sw)) * 8);
    }
#pragma unroll
    for (int mb = 0; mb < 2; ++mb)
#pragma unroll
      for (int nb = 0; nb < 4; ++nb) {
        acc[mb][nb] = __builtin_amdgcn_mfma_f32_16x16x32_bf16(af[mb][0], bf[nb][0], acc[mb][nb], 0, 0, 0);
        acc[mb][nb] = __builtin_amdgcn_mfma_f32_16x16x32_bf16(af[mb][1], bf[nb][1], acc[mb][nb], 0, 0, 0);
      }
  }

#pragma unroll
  for (int mb = 0; mb < 2; ++mb)
#pragma unroll
    for (int nb = 0; nb < 4; ++nb)
#pragma unroll
      for (int r = 0; r < 4; ++r)
        out[(size_t)(m0 + wm * 32 + mb * 16 + quad * 4 + r) * HIDDEN +
            n0 + wn * 64 + nb * 16 + l15] = acc[mb][nb][r];
}

// ---------------- launch ----------------

extern "C" void kernel_launch(void* const* d_in, const int* in_sizes, int n_in,
                              void* d_out, int out_size, void* d_ws, size_t ws_size,
                              hipStream_t stream) {
  (void)in_sizes; (void)n_in; (void)out_size; (void)ws_size;
  const float* hidden = (const float*)d_in[0];
  const int* pos      = (const int*)d_in[1];
  const float* Wq     = (const float*)d_in[2];
  const float* Wk     = (const float*)d_in[3];
  const float* Wv     = (const float*)d_in[4];
  const float* Wo     = (const float*)d_in[5];
  float* out = (float*)d_out;

  char* ws = (char*)d_ws;
  ushort_t* hb   = (ushort_t*)(ws);               // [8192][896] bf16   14,680,064
  ushort_t* wT   = (ushort_t*)(ws + 14680064);    // [1152][896] bf16    2,064,384
  float2*   ctab = (float2*)  (ws + 16744448);    // [2048][32]            524,288
  ushort_t* Qg   = (ushort_t*)(ws + 17268736);    // [4][14][2048][64]  14,680,064
  ushort_t* Kg   = (ushort_t*)(ws + 31948800);    // [4][2][2048][64]    2,097,152
  ushort_t* Vtg  = (ushort_t*)(ws + 34045952);    // [4][2][64][2048]    2,097,152
  ushort_t* attn = (ushort_t*)(ws + 36143104);    // [8192][896] bf16   14,680,064
  ushort_t* woT  = (ushort_t*)(ws + 50823168);    // [896][896] bf16     1,605,632

  k_prep<<<9216, dim3(32, 8), 0, stream>>>(hidden, hb, Wq, Wk, Wv, Wo, wT, woT, ctab);
  k_qkv<<<1152, 256, 0, stream>>>(hb, wT, pos, ctab, Qg, Kg, Vtg);
  k_attn<<<896, 256, 0, stream>>>(Qg, Kg, Vtg, attn);
  k_oproj<<<896, 256, 0, stream>>>(attn, woT, out);
}

// Round 13
// 226.323 us; speedup vs baseline: 1.6170x; 1.6091x over previous
//
#include <hip/hip_runtime.h>
#include <hip/hip_bf16.h>
#include <math.h>

typedef unsigned short ushort_t;
typedef __bf16 bf16x8 __attribute__((ext_vector_type(8)));
typedef float f32x4 __attribute__((ext_vector_type(4)));

#define HIDDEN 896
#define NQH 14
#define NKVH 2
#define HD 64
#define SEQ 2048
#define NBATCH 4

__device__ inline ushort_t f2bf(float x) {
  union { float f; unsigned u; } c; c.f = x;
  unsigned r = c.u + 0x7FFFu + ((c.u >> 16) & 1u);
  return (ushort_t)(r >> 16);
}

__device__ inline unsigned pack2bf(float a, float b) {
  union { float f; unsigned u; } ca, cb; ca.f = a; cb.f = b;
  unsigned ua = ca.u + 0x8000u, ub = cb.u + 0x8000u;
  return __builtin_amdgcn_perm(ub, ua, 0x07060302);
}

__device__ inline bf16x8 ldfrag(const ushort_t* p) {
  return *reinterpret_cast<const bf16x8*>(p);
}

__device__ inline void async16(const ushort_t* g, ushort_t* l) {
  __builtin_amdgcn_global_load_lds(
      (const __attribute__((address_space(1))) void*)g,
      (__attribute__((address_space(3))) void*)l, 16, 0, 0);
}

// ---------------- prep ----------------

__device__ inline void transpose_sec(const float* __restrict__ in, ushort_t* __restrict__ out,
                                     int K, int N, int bx, int by) {
  __shared__ float tile[32][33];
  int k0 = by * 32, n0 = bx * 32;
  for (int r = threadIdx.y; r < 32; r += 8) {
    int k = k0 + r, n = n0 + threadIdx.x;
    tile[r][threadIdx.x] = (k < K && n < N) ? in[(size_t)k * N + n] : 0.f;
  }
  __syncthreads();
  for (int r = threadIdx.y; r < 32; r += 8) {
    int n = n0 + r, k = k0 + threadIdx.x;
    if (n < N && k < K) out[(size_t)n * K + k] = f2bf(tile[threadIdx.x][r]);
  }
}

__global__ void k_prep(const float* __restrict__ hidden, ushort_t* __restrict__ hb,
                       const float* __restrict__ Wq, const float* __restrict__ Wk,
                       const float* __restrict__ Wv, const float* __restrict__ Wo,
                       ushort_t* __restrict__ wT, ushort_t* __restrict__ woT,
                       float2* __restrict__ ctab) {
  const int blk = blockIdx.x;
  const int tid = threadIdx.y * 32 + threadIdx.x;
  if (blk < 7168) {
    int i = blk * 256 + tid;
    float4 v = reinterpret_cast<const float4*>(hidden)[i];
    ushort4 o;
    o.x = f2bf(v.x); o.y = f2bf(v.y); o.z = f2bf(v.z); o.w = f2bf(v.w);
    reinterpret_cast<ushort4*>(hb)[i] = o;
  } else if (blk < 7424) {
    int idx = (blk - 7168) * 256 + tid;
    int s = idx >> 5, dp = idx & 31;
    float inv = exp2f(-(float)dp * 0.41524101186092596f);
    float ang = (float)s * inv;
    float sn, cn;
    sincosf(ang, &sn, &cn);
    ctab[idx] = make_float2(cn, sn);
  } else if (blk < 8208) {
    int t = blk - 7424;
    transpose_sec(Wq, wT, 896, 896, t % 28, t / 28);
  } else if (blk < 8320) {
    int t = blk - 8208;
    transpose_sec(Wk, wT + (size_t)896 * 896, 896, 128, t % 4, t / 4);
  } else if (blk < 8432) {
    int t = blk - 8320;
    transpose_sec(Wv, wT + (size_t)1024 * 896, 896, 128, t % 4, t / 4);
  } else {
    int t = blk - 8432;
    transpose_sec(Wo, woT, 896, 896, t % 28, t / 28);
  }
}

// ---------------- QKV projection + RoPE (64x64 tiles, 16x64 wave-tile) ----------
// grid: 2304 blocks 1D (128 m-tiles x 18 n-sections), XCD-swizzled; ~9 blocks/CU
// so per-kt vmcnt(0)+barrier drains overlap across co-resident blocks.
// sect 0..13 = Q head; 14..15 = K kvh; 16..17 = V kvh.
__global__ __launch_bounds__(256) void k_qkv(
    const ushort_t* __restrict__ hb,
    const ushort_t* __restrict__ wT,
    const int* __restrict__ pos_ids,
    const float2* __restrict__ ctab,
    ushort_t* __restrict__ Qg,
    ushort_t* __restrict__ Kg,
    ushort_t* __restrict__ Vtg) {
  __shared__ ushort_t smem[8192];   // sa [0,4096) 64x64, sbb [4096,8192) 64x64
  ushort_t* sa = smem;
  ushort_t* sbb = smem + 4096;

  const int f = blockIdx.x;
  const int x = f & 7, s8 = f >> 3;       // s8: 0..287
  const int sect = s8 % 18;
  const int mt = (s8 / 18) * 8 + x;       // 0..127
  const int nt0 = sect * 64;
  const int m0 = mt * 64;
  const int tid = threadIdx.x;
  const int wave = tid >> 6, lane = tid & 63;
  const int l15 = lane & 15, quad = lane >> 4;
  const int sw = l15 & 7;

  f32x4 acc[4];
  const f32x4 z4 = {0.f, 0.f, 0.f, 0.f};
#pragma unroll
  for (int b = 0; b < 4; ++b) acc[b] = z4;

  for (int kt = 0; kt < 14; ++kt) {
    const int k0 = kt * 64;
    __syncthreads();
#pragma unroll
    for (int i = 0; i < 2; ++i) {
      int id = i * 256 + tid;
      int row = id >> 3;
      int cs = (id & 7) ^ (row & 7);
      async16(hb + (size_t)(m0 + row) * HIDDEN + k0 + cs * 8, sa + (i * 256 + wave * 64) * 8);
      async16(wT + (size_t)(nt0 + row) * HIDDEN + k0 + cs * 8, sbb + (i * 256 + wave * 64) * 8);
    }
    __syncthreads();
#pragma unroll
    for (int kc = 0; kc < 2; ++kc) {
      int c = kc * 4 + quad;
      bf16x8 af = ldfrag(sa + ((wave * 16 + l15) * 8 + (c ^ sw)) * 8);
      bf16x8 bf[4];
#pragma unroll
      for (int nb = 0; nb < 4; ++nb)
        bf[nb] = ldfrag(sbb + ((nb * 16 + l15) * 8 + (c ^ sw)) * 8);
#pragma unroll
      for (int nb = 0; nb < 4; ++nb)
        acc[nb] = __builtin_amdgcn_mfma_f32_16x16x32_bf16(af, bf[nb], acc[nb], 0, 0, 0);
    }
  }

  if (sect < 16) {
    const bool isQ = sect < 14;
    const float csc = isQ ? 0.125f * 1.4426950408889634f : 1.0f;
    ushort_t* dst = isQ ? Qg : Kg;
    const int nheads = isQ ? NQH : NKVH;
    const int hh = isQ ? sect : sect - 14;
#pragma unroll
    for (int r = 0; r < 4; ++r) {
      int token = m0 + wave * 16 + quad * 4 + r;
      int b = token >> 11, s = token & 2047;
      int pos = pos_ids[token];
      size_t base = ((size_t)(b * nheads + hh) * SEQ + s) * HD;
#pragma unroll
      for (int nb = 0; nb < 2; ++nb) {
        float2 cs = ctab[pos * 32 + nb * 16 + l15];
        float x0 = acc[nb][r];
        float x1 = acc[nb + 2][r];
        float y0 = (x0 * cs.x - x1 * cs.y) * csc;
        float y1 = (x1 * cs.x + x0 * cs.y) * csc;
        dst[base + nb * 16 + l15]      = f2bf(y0);
        dst[base + nb * 16 + l15 + 32] = f2bf(y1);
      }
    }
  } else {
    const int kvh = sect - 16;
    __syncthreads();
    ushort_t* vt = smem;  // 64 d-rows x 64 tokens = 8192B
    {
      int tl = wave * 16 + quad * 4;            // token base (r=0..3)
      int chunk = tl >> 3, ofs = tl & 7;        // ofs = 0 or 4
#pragma unroll
      for (int nb = 0; nb < 4; ++nb) {
        int row = nb * 16 + l15;                // d
        int slot = chunk ^ (row & 7);
        ushort_t* p = vt + row * 64 + slot * 8 + ofs;
        *reinterpret_cast<unsigned*>(p)     = pack2bf(acc[nb][0], acc[nb][1]);
        *reinterpret_cast<unsigned*>(p + 2) = pack2bf(acc[nb][2], acc[nb][3]);
      }
    }
    __syncthreads();
    const int bb = m0 >> 11, s0 = m0 & 2047;
#pragma unroll
    for (int i = 0; i < 2; ++i) {
      int id = i * 256 + tid;          // 512 chunks: 64 rows x 8 chunks
      int row = id >> 3, ch = id & 7;
      int slot = ch ^ (row & 7);
      uint4 v = *reinterpret_cast<const uint4*>(vt + row * 64 + slot * 8);
      *reinterpret_cast<uint4*>(Vtg + ((size_t)(bb * NKVH + kvh) * HD + row) * SEQ + s0 + ch * 8) = v;
    }
  }
}

// ---------------- flash attention (R9 measured-best: LDS-staged, XCD-swizzled) -------
// grid: 896 blocks x 256 threads. XCD x owns (b,kvh): b=x>>1, kvh=x&1. 4 waves x 32q.
// R6/R11/R12 verdict: direct-global K/V can't be latency-hidden at HIP level (the
// compiler sinks source-level register prefetches); global_load_lds DMA is the only
// working latency-hiding path. Do not touch this kernel.
__global__ __launch_bounds__(256) void k_attn(
    const ushort_t* __restrict__ Qg,
    const ushort_t* __restrict__ Kg,
    const ushort_t* __restrict__ Vtg,
    ushort_t* __restrict__ attn) {
  __shared__ ushort_t kbuf[64 * 64];
  __shared__ ushort_t vbuf[64 * 64];
  __shared__ ushort_t pbuf[4][32 * 72];

  const int f = blockIdx.x;
  const int x = f & 7, s8 = f >> 3;     // s8: 0..111
  const int lh = s8 % 7;
  const int qt = s8 / 7;                // 0..15
  const int b = x >> 1, kvh = x & 1;
  const int h = kvh * 7 + lh;
  const int bh = b * NQH + h;
  const int tid = threadIdx.x;
  const int wave = tid >> 6, lane = tid & 63;
  const int l15 = lane & 15, quad = lane >> 4;
  const int q0 = qt * 128;

  bf16x8 qf[2][2];
#pragma unroll
  for (int qs = 0; qs < 2; ++qs) {
    const size_t qb = ((size_t)bh * SEQ + q0 + wave * 32 + qs * 16 + l15) * HD + quad * 8;
    qf[qs][0] = ldfrag(Qg + qb);
    qf[qs][1] = ldfrag(Qg + qb + 32);
  }

  const size_t kbase = (size_t)(b * NKVH + kvh) * SEQ * HD;
  const size_t vbase = (size_t)(b * NKVH + kvh) * HD * SEQ;

  const int srow = tid >> 3;
  const int sc0 = (tid & 7) ^ (srow & 7);
  const int srow2 = (256 + tid) >> 3;
  const int sc2 = (tid & 7) ^ (srow2 & 7);
  const int sbase1 = wave * 64 * 8;
  const int sbase2 = (256 + wave * 64) * 8;

  float l_part[2] = {0.f, 0.f};
  f32x4 o[2][4];
  const f32x4 z4 = {0.f, 0.f, 0.f, 0.f};
#pragma unroll
  for (int qs = 0; qs < 2; ++qs)
#pragma unroll
    for (int nb = 0; nb < 4; ++nb) o[qs][nb] = z4;

  ushort_t* pw = pbuf[wave];

  for (int jt = 0; jt < 32; ++jt) {
    const int s0 = jt * 64;
    __syncthreads();
    async16(Kg + kbase + (size_t)(s0 + srow) * HD + sc0 * 8, kbuf + sbase1);
    async16(Vtg + vbase + (size_t)srow * SEQ + s0 + sc0 * 8, vbuf + sbase1);
    async16(Kg + kbase + (size_t)(s0 + srow2) * HD + sc2 * 8, kbuf + sbase2);
    async16(Vtg + vbase + (size_t)srow2 * SEQ + s0 + sc2 * 8, vbuf + sbase2);
    __syncthreads();

#pragma unroll
    for (int nb = 0; nb < 4; ++nb) {
      int row = nb * 16 + l15;
      int sw = row & 7;
      bf16x8 kf0 = ldfrag(kbuf + (row * 8 + (quad ^ sw)) * 8);
      bf16x8 kf1 = ldfrag(kbuf + (row * 8 + ((4 + quad) ^ sw)) * 8);
#pragma unroll
      for (int qs = 0; qs < 2; ++qs) {
        f32x4 t = z4;
        t = __builtin_amdgcn_mfma_f32_16x16x32_bf16(kf0, qf[qs][0], t, 0, 0, 0);
        t = __builtin_amdgcn_mfma_f32_16x16x32_bf16(kf1, qf[qs][1], t, 0, 0, 0);
        float p0 = __builtin_amdgcn_exp2f(t[0]);
        float p1 = __builtin_amdgcn_exp2f(t[1]);
        float p2 = __builtin_amdgcn_exp2f(t[2]);
        float p3 = __builtin_amdgcn_exp2f(t[3]);
        l_part[qs] += (p0 + p1) + (p2 + p3);
        uint2 d;
        d.x = pack2bf(p0, p1);
        d.y = pack2bf(p2, p3);
        *reinterpret_cast<uint2*>(pw + (qs * 16 + l15) * 72 + nb * 16 + quad * 4) = d;
      }
    }

    bf16x8 pf[2][2];
#pragma unroll
    for (int qs = 0; qs < 2; ++qs) {
      pf[qs][0] = ldfrag(pw + (qs * 16 + l15) * 72 + quad * 8);
      pf[qs][1] = ldfrag(pw + (qs * 16 + l15) * 72 + 32 + quad * 8);
    }
#pragma unroll
    for (int nb = 0; nb < 4; ++nb) {
      int row = nb * 16 + l15;
      int sw = row & 7;
      bf16x8 vf0 = ldfrag(vbuf + (row * 8 + (quad ^ sw)) * 8);
      bf16x8 vf1 = ldfrag(vbuf + (row * 8 + ((4 + quad) ^ sw)) * 8);
#pragma unroll
      for (int qs = 0; qs < 2; ++qs) {
        o[qs][nb] = __builtin_amdgcn_mfma_f32_16x16x32_bf16(pf[qs][0], vf0, o[qs][nb], 0, 0, 0);
        o[qs][nb] = __builtin_amdgcn_mfma_f32_16x16x32_bf16(pf[qs][1], vf1, o[qs][nb], 0, 0, 0);
      }
    }
  }

#pragma unroll
  for (int qs = 0; qs < 2; ++qs) {
    float s = l_part[qs];
    s += __shfl_xor(s, 16);
    s += __shfl_xor(s, 32);
    l_part[qs] = s;
  }

#pragma unroll
  for (int qs = 0; qs < 2; ++qs) {
    float il = 1.0f / l_part[qs];
#pragma unroll
    for (int r = 0; r < 4; ++r) {
      float inv = __shfl(il, quad * 4 + r);
      int qg = q0 + wave * 32 + qs * 16 + quad * 4 + r;
#pragma unroll
      for (int nb = 0; nb < 4; ++nb) {
        float val = o[qs][nb][r] * inv;
        attn[(size_t)(b * SEQ + qg) * (NQH * HD) + h * HD + nb * 16 + l15] = f2bf(val);
      }
    }
  }
}

// ---------------- output projection (64x64 tiles, 16x64 wave-tile) ----------------
// grid: 1792 blocks 1D (128 m-tiles x 14 n-sections); ~7 blocks/CU.
__global__ __launch_bounds__(256) void k_oproj(
    const ushort_t* __restrict__ attn,
    const ushort_t* __restrict__ woT,
    float* __restrict__ out) {
  __shared__ ushort_t smem[8192];
  ushort_t* sa = smem;
  ushort_t* sbb = smem + 4096;

  const int f = blockIdx.x;
  const int x = f & 7, s8 = f >> 3;   // s8: 0..223
  const int n_sect = s8 % 14;
  const int mt = (s8 / 14) * 8 + x;   // 0..127
  const int n0 = n_sect * 64;
  const int m0 = mt * 64;
  const int tid = threadIdx.x;
  const int wave = tid >> 6, lane = tid & 63;
  const int l15 = lane & 15, quad = lane >> 4;
  const int sw = l15 & 7;

  f32x4 acc[4];
  const f32x4 z4 = {0.f, 0.f, 0.f, 0.f};
#pragma unroll
  for (int b = 0; b < 4; ++b) acc[b] = z4;

  for (int kt = 0; kt < 14; ++kt) {
    const int k0 = kt * 64;
    __syncthreads();
#pragma unroll
    for (int i = 0; i < 2; ++i) {
      int id = i * 256 + tid;
      int row = id >> 3;
      int cs = (id & 7) ^ (row & 7);
      async16(attn + (size_t)(m0 + row) * HIDDEN + k0 + cs * 8, sa + (i * 256 + wave * 64) * 8);
      async16(woT + (size_t)(n0 + row) * HIDDEN + k0 + cs * 8, sbb + (i * 256 + wave * 64) * 8);
    }
    __syncthreads();
#pragma unroll
    for (int kc = 0; kc < 2; ++kc) {
      int c = kc * 4 + quad;
      bf16x8 af = ldfrag(sa + ((wave * 16 + l15) * 8 + (c ^ sw)) * 8);
      bf16x8 bf[4];
#pragma unroll
      for (int nb = 0; nb < 4; ++nb)
        bf[nb] = ldfrag(sbb + ((nb * 16 + l15) * 8 + (c ^ sw)) * 8);
#pragma unroll
      for (int nb = 0; nb < 4; ++nb)
        acc[nb] = __builtin_amdgcn_mfma_f32_16x16x32_bf16(af, bf[nb], acc[nb], 0, 0, 0);
    }
  }

#pragma unroll
  for (int nb = 0; nb < 4; ++nb)
#pragma unroll
    for (int r = 0; r < 4; ++r)
      out[(size_t)(m0 + wave * 16 + quad * 4 + r) * HIDDEN +
          n0 + nb * 16 + l15] = acc[nb][r];
}

// ---------------- launch ----------------

extern "C" void kernel_launch(void* const* d_in, const int* in_sizes, int n_in,
                              void* d_out, int out_size, void* d_ws, size_t ws_size,
                              hipStream_t stream) {
  (void)in_sizes; (void)n_in; (void)out_size; (void)ws_size;
  const float* hidden = (const float*)d_in[0];
  const int* pos      = (const int*)d_in[1];
  const float* Wq     = (const float*)d_in[2];
  const float* Wk     = (const float*)d_in[3];
  const float* Wv     = (const float*)d_in[4];
  const float* Wo     = (const float*)d_in[5];
  float* out = (float*)d_out;

  char* ws = (char*)d_ws;
  ushort_t* hb   = (ushort_t*)(ws);               // [8192][896] bf16   14,680,064
  ushort_t* wT   = (ushort_t*)(ws + 14680064);    // [1152][896] bf16    2,064,384
  float2*   ctab = (float2*)  (ws + 16744448);    // [2048][32]            524,288
  ushort_t* Qg   = (ushort_t*)(ws + 17268736);    // [4][14][2048][64]  14,680,064
  ushort_t* Kg   = (ushort_t*)(ws + 31948800);    // [4][2][2048][64]    2,097,152
  ushort_t* Vtg  = (ushort_t*)(ws + 34045952);    // [4][2][64][2048]    2,097,152
  ushort_t* attn = (ushort_t*)(ws + 36143104);    // [8192][896] bf16   14,680,064
  ushort_t* woT  = (ushort_t*)(ws + 50823168);    // [896][896] bf16     1,605,632

  k_prep<<<9216, dim3(32, 8), 0, stream>>>(hidden, hb, Wq, Wk, Wv, Wo, wT, woT, ctab);
  k_qkv<<<2304, 256, 0, stream>>>(hb, wT, pos, ctab, Qg, Kg, Vtg);
  k_attn<<<896, 256, 0, stream>>>(Qg, Kg, Vtg, attn);
  k_oproj<<<1792, 256, 0, stream>>>(attn, woT, out);
}